// Round 9
// baseline (135.307 us; speedup 1.0000x reference)
//
#include <hip/hip_runtime.h>

// focal_loss scalar reduction:
//   out = COEF * sum_i [ idx==0 ? log(p_i) : idx==1 ? log1p(-p_i) : 0 ]
//
// R7 confirmed: the ~3.2 TB/s read throttle is PER-PATH (VGPR-return vs
// LDS-DMA credit pools). Splitting idx->DMA / p->ntVGPR gave ~4.8 TB/s.
// R8 crashed on an addressing bug (second DMA chunk at +1024 elements
// instead of +256 -> OOB on the last tile). R9 = R8 with the fix: 2 tiles,
// fully unrolled, ALL 8 loads (4 DMA + 4 ntVGPR) issued before ONE drain
// (4 KB/wave in flight, 2 KB/path). Partial vmcnt waits deliberately
// avoided: compiler reordering of nt loads vs DMA builtins would break a
// manual vmcnt count.

static constexpr int BLOCK  = 256;        // 4 waves
static constexpr int GRID   = 4096;
static constexpr int TILE_E = 2048;       // elems per block-iter
static constexpr int FITERS = 2;          // GRID*TILE_E*FITERS == 16777216
static constexpr float COEF = 0.004f;     // WF * (1-0.8)^2
static constexpr float LN2  = 0.69314718055994530942f;

typedef float fvec4 __attribute__((ext_vector_type(4)));
typedef int   ivec4 __attribute__((ext_vector_type(4)));

typedef const __attribute__((address_space(1))) unsigned int gu32;
typedef __attribute__((address_space(3))) unsigned int lu32;

__device__ __forceinline__ float sel_log2(float pv, int iv) {
    return __log2f((iv == 0) ? pv : 1.0f - pv);
}

__global__ __launch_bounds__(BLOCK) void fl_partial(
    const float* __restrict__ p,
    const int*   __restrict__ idx,
    float*       __restrict__ partials,
    int n)
{
    __shared__ int ibuf[FITERS][TILE_E];   // 16 KB/block -> still 8 blocks/CU
    const int lane = threadIdx.x & 63;
    const int wave = threadIdx.x >> 6;

    float acc = 0.0f;

    if (n == GRID * TILE_E * FITERS) {
        const int woff = wave * 512;       // wave's elem offset inside a tile
        const long b0 = (long)blockIdx.x * TILE_E + woff;               // t=0
        const long b1 = ((long)GRID + blockIdx.x) * TILE_E + woff;      // t=1
        const fvec4* pb0 = (const fvec4*)(p + b0);
        const fvec4* pb1 = (const fvec4*)(p + b1);

        // Issue all 8 loads (4 DMA + 4 ntVGPR, interleaved) before one drain.
        // Each DMA covers 256 elements (64 lanes x 16 B).
        __builtin_amdgcn_global_load_lds((gu32*)(idx + b0),       (lu32*)(&ibuf[0][woff]),       16, 0, 0);
        fvec4 pv00 = __builtin_nontemporal_load(pb0 + lane);
        __builtin_amdgcn_global_load_lds((gu32*)(idx + b0 + 256), (lu32*)(&ibuf[0][woff + 256]), 16, 0, 0);
        fvec4 pv01 = __builtin_nontemporal_load(pb0 + 64 + lane);
        __builtin_amdgcn_global_load_lds((gu32*)(idx + b1),       (lu32*)(&ibuf[1][woff]),       16, 0, 0);
        fvec4 pv10 = __builtin_nontemporal_load(pb1 + lane);
        __builtin_amdgcn_global_load_lds((gu32*)(idx + b1 + 256), (lu32*)(&ibuf[1][woff + 256]), 16, 0, 0);
        fvec4 pv11 = __builtin_nontemporal_load(pb1 + 64 + lane);

        __builtin_amdgcn_s_waitcnt(0);     // single reorder-proof drain

        ivec4 iv00 = *(const ivec4*)(&ibuf[0][woff       + lane * 4]);
        ivec4 iv01 = *(const ivec4*)(&ibuf[0][woff + 256 + lane * 4]);
        ivec4 iv10 = *(const ivec4*)(&ibuf[1][woff       + lane * 4]);
        ivec4 iv11 = *(const ivec4*)(&ibuf[1][woff + 256 + lane * 4]);

        acc += sel_log2(pv00.x, iv00.x); acc += sel_log2(pv00.y, iv00.y);
        acc += sel_log2(pv00.z, iv00.z); acc += sel_log2(pv00.w, iv00.w);
        acc += sel_log2(pv01.x, iv01.x); acc += sel_log2(pv01.y, iv01.y);
        acc += sel_log2(pv01.z, iv01.z); acc += sel_log2(pv01.w, iv01.w);
        acc += sel_log2(pv10.x, iv10.x); acc += sel_log2(pv10.y, iv10.y);
        acc += sel_log2(pv10.z, iv10.z); acc += sel_log2(pv10.w, iv10.w);
        acc += sel_log2(pv11.x, iv11.x); acc += sel_log2(pv11.y, iv11.y);
        acc += sel_log2(pv11.z, iv11.z); acc += sel_log2(pv11.w, iv11.w);
    } else {
        // Generic fallback (R5 structure, known-correct).
        const fvec4* __restrict__ p4 = reinterpret_cast<const fvec4*>(p);
        const ivec4* __restrict__ i4 = reinterpret_cast<const ivec4*>(idx);
        const int n4 = n >> 2;
        const int stride = GRID * BLOCK;
        for (int i = blockIdx.x * BLOCK + threadIdx.x; i < n4; i += stride) {
            fvec4 pv = __builtin_nontemporal_load(&p4[i]);
            ivec4 iv = __builtin_nontemporal_load(&i4[i]);
            acc += sel_log2(pv.x, iv.x);
            acc += sel_log2(pv.y, iv.y);
            acc += sel_log2(pv.z, iv.z);
            acc += sel_log2(pv.w, iv.w);
        }
        if (blockIdx.x == 0 && threadIdx.x == 0)
            for (int j = n4 << 2; j < n; ++j)
                acc += sel_log2(p[j], idx[j]);
    }

    // wave-64 butterfly reduce
    for (int off = 32; off > 0; off >>= 1)
        acc += __shfl_down(acc, off, 64);

    __shared__ float ws[BLOCK / 64];
    if (lane == 0) ws[wave] = acc;
    __syncthreads();
    if (threadIdx.x == 0)
        partials[blockIdx.x] = ws[0] + ws[1] + ws[2] + ws[3];
}

__global__ __launch_bounds__(BLOCK) void fl_final(
    const float* __restrict__ partials,
    float*       __restrict__ out)
{
    float acc = 0.0f;
    for (int i = threadIdx.x; i < GRID; i += BLOCK)
        acc += partials[i];
    for (int off = 32; off > 0; off >>= 1)
        acc += __shfl_down(acc, off, 64);

    __shared__ float ws[BLOCK / 64];
    const int lane = threadIdx.x & 63;
    const int wave = threadIdx.x >> 6;
    if (lane == 0) ws[wave] = acc;
    __syncthreads();
    if (threadIdx.x == 0)
        out[0] = (ws[0] + ws[1] + ws[2] + ws[3]) * (COEF * LN2);
}

extern "C" void kernel_launch(void* const* d_in, const int* in_sizes, int n_in,
                              void* d_out, int out_size, void* d_ws, size_t ws_size,
                              hipStream_t stream)
{
    const float* p   = (const float*)d_in[0];
    const int*   idx = (const int*)d_in[1];
    float* partials  = (float*)d_ws;      // GRID floats = 16 KB scratch
    const int n = in_sizes[0];

    fl_partial<<<GRID, BLOCK, 0, stream>>>(p, idx, partials, n);
    fl_final<<<1, BLOCK, 0, stream>>>(partials, (float*)d_out);
}